// Round 7
// baseline (544.903 us; speedup 1.0000x reference)
//
#include <hip/hip_runtime.h>
#include <hip/hip_bf16.h>

typedef __attribute__((ext_vector_type(8))) short bf16x8;
typedef __attribute__((ext_vector_type(4))) float f32x4;

__device__ __forceinline__ unsigned short f2bf(float f) {
  __hip_bfloat16 h = __float2bfloat16(f);
  return *reinterpret_cast<unsigned short*>(&h);
}

__device__ __forceinline__ void gld_lds16(void* lds, const void* g) {
  __builtin_amdgcn_global_load_lds(
      (const __attribute__((address_space(1))) unsigned int*)g,
      (__attribute__((address_space(3))) unsigned int*)lds, 16, 0, 0);
}

// ---------------------------------------------------------------------------
// Kernel 1: offset conv (fp64 accumulate) + gather + fp32->bf16 cast.
// (unchanged — isolate the k3 scheduling delta)
// ---------------------------------------------------------------------------
__global__ __launch_bounds__(256) void k1_offs_gather(
    const float* __restrict__ in, const float* __restrict__ w_off,
    const float* __restrict__ b_off, unsigned short* __restrict__ samp) {
  __shared__ float tile[3][128][34];
  __shared__ float wlf[9 * 64];
  __shared__ double dsum[2][128][2];
  __shared__ int lin_lds[128];

  const int bid = blockIdx.x;
  const int b = bid >> 7, h = bid & 127;
  const int t = threadIdx.x;
  const int w = t & 127, half = t >> 7, ch0 = half * 16;

  double a0 = 0.0, a1 = 0.0;

  for (int c0 = 0; c0 < 256; c0 += 32) {
    __syncthreads();
    for (int i = t; i < 576; i += 256) {
      int tap = i >> 6, r = i & 63;
      wlf[i] = w_off[tap * 512 + c0 * 2 + r];
    }
    for (int dr = 0; dr < 3; ++dr) {
      int hh = h + dr - 1;
      if ((unsigned)hh < 128u) {
        const float* rbase = in + ((size_t)(b * 128 + hh) * 128) * 256 + c0;
        #pragma unroll
        for (int it = 0; it < 4; ++it) {
          int idx = it * 256 + t;
          int ww = idx >> 3, cq = idx & 7;
          const float4 v = *(const float4*)(rbase + ww * 256 + cq * 4);
          float* dst = &tile[dr][ww][cq * 4];
          *(float2*)dst = make_float2(v.x, v.y);
          *(float2*)(dst + 2) = make_float2(v.z, v.w);
        }
      } else {
        #pragma unroll
        for (int it = 0; it < 4; ++it) {
          int idx = it * 256 + t;
          int ww = idx >> 3, cq = idx & 7;
          float* dst = &tile[dr][ww][cq * 4];
          *(float2*)dst = make_float2(0.f, 0.f);
          *(float2*)(dst + 2) = make_float2(0.f, 0.f);
        }
      }
    }
    __syncthreads();
    #pragma unroll
    for (int dr = 0; dr < 3; ++dr) {
      #pragma unroll
      for (int dc = 0; dc < 3; ++dc) {
        int wsrc = w + dc - 1;
        if ((unsigned)wsrc >= 128u) continue;
        const float2* tp2 = (const float2*)&tile[dr][wsrc][ch0];
        const float2* wp2 = (const float2*)&wlf[(dr * 3 + dc) * 64 + ch0 * 2];
        #pragma unroll
        for (int c2 = 0; c2 < 8; ++c2) {
          float2 v = tp2[c2];
          float2 wa = wp2[2 * c2];
          float2 wb = wp2[2 * c2 + 1];
          a0 += (double)v.x * (double)wa.x;
          a1 += (double)v.x * (double)wa.y;
          a0 += (double)v.y * (double)wb.x;
          a1 += (double)v.y * (double)wb.y;
        }
      }
    }
  }
  dsum[half][w][0] = a0;
  dsum[half][w][1] = a1;
  __syncthreads();
  if (t < 128) {
    double o0 = dsum[0][t][0] + dsum[1][t][0] + (double)b_off[0];
    double o1 = dsum[0][t][1] + dsum[1][t][1] + (double)b_off[1];
    double yd = (double)h + o0;
    double xd = (double)t + o1;
    yd = yd < 0.0 ? 0.0 : (yd > 127.0 ? 127.0 : yd);
    xd = xd < 0.0 ? 0.0 : (xd > 127.0 ? 127.0 : xd);
    int y = (int)yd, x = (int)xd;
    lin_lds[t] = y * 128 + x;
  }
  __syncthreads();
  const float* imgbase = in + (size_t)b * 16384 * 256;
  unsigned short* obase = samp + (size_t)bid * 128 * 256;
  for (int it = 0; it < 32; ++it) {
    int idx = it * 256 + t;
    int px = idx >> 6, cv = idx & 63;
    const float4 v = *(const float4*)(imgbase + (size_t)lin_lds[px] * 256 + cv * 4);
    ushort4 o;
    o.x = f2bf(v.x); o.y = f2bf(v.y); o.z = f2bf(v.z); o.w = f2bf(v.w);
    *(ushort4*)(obase + px * 256 + cv * 4) = o;
  }
}

// ---------------------------------------------------------------------------
// Kernel 2: w_def (3,3,256,256)[tap][k][n] fp32 -> wT[tap][n][k] bf16
// ---------------------------------------------------------------------------
__global__ __launch_bounds__(256) void k2_wT(const float* __restrict__ wdef,
                                             unsigned short* __restrict__ wT) {
  int g = blockIdx.x * 256 + threadIdx.x;
  int tap = g >> 16;
  int n = (g >> 8) & 255;
  int k = g & 255;
  wT[g] = f2bf(wdef[((size_t)tap * 256 + k) * 256 + n]);
}

// ---------------------------------------------------------------------------
// Kernel 3: implicit-GEMM 3x3 SAME conv, bf16 MFMA, 2-phase BURST schedule.
// Same geometry/ring/ledger as rounds 4-6. New: after each leading barrier,
// explicit lgkmcnt(0) + register LAUNDER (asm "+v" on every fragment) +
// sched_barrier(0) so the 16-MFMA cluster issues with ZERO interior waitcnts
// into the deep MAI queue; wave reaches the trailing barrier while the pipe
// drains, and the next phase's ds_reads are serviced under that drain.
// Consecutive phases write disjoint acc quadrants (issue-independent).
// vmcnt ledger identical to round 5/6 (stage split 2+2 preserves counts):
// at phase B after issuing its 2 loads, outstanding = 12; vmcnt(8) drains
// stage(t+1) (oldest 4). Tail VM = 4 (t=69), 0 (t=70/71).
// ---------------------------------------------------------------------------
__global__ __launch_bounds__(512, 2) void k3_conv(
    const unsigned short* __restrict__ samp, const unsigned short* __restrict__ wT,
    const float* __restrict__ b_def, float* __restrict__ out,
    const unsigned short* __restrict__ zerobuf) {
  __shared__ __align__(16) unsigned char smem[131072];  // A ring 64KB | B ring 64KB

  // T1: bijective XCD swizzle (grid 1024 % 8 == 0)
  const int bid0 = blockIdx.x;
  const int mt = (bid0 & 7) * 128 + (bid0 >> 3);
  const int bimg = mt >> 6;
  const int h0 = (mt & 63) * 2;

  const int tid = threadIdx.x;
  const int lane = tid & 63, wave = tid >> 6;
  const int wr = wave >> 2, wc = wave & 3;
  const int r15 = lane & 15, g4 = lane >> 4;
  const int g4eff = g4 ^ ((r15 >> 1) & 3);   // read-side bank swizzle

  int aoff[8], boff[4];
  #pragma unroll
  for (int mi = 0; mi < 8; ++mi)
    aoff[mi] = (wr * 128 + mi * 16 + r15) * 32 + g4eff * 8;
  #pragma unroll
  for (int ni = 0; ni < 4; ++ni)
    boff[ni] = (wc * 64 + ni * 16 + r15) * 32 + g4eff * 8;

  // ---- staging precompute (hoisted) ----
  const int chq = tid & 3;
  const int pix = tid >> 2;
  const int chs = chq ^ ((pix >> 1) & 3);  // inverse swizzle on global source
  const unsigned short* pA[2];
  const unsigned short* pB[2];
  unsigned vmask[2];
  #pragma unroll
  for (int it = 0; it < 2; ++it) {
    const int hh = h0 + it;
    pA[it] = samp + ((size_t)(bimg * 128 + hh) * 128 + pix) * 256 + chs * 8;
    pB[it] = wT + (size_t)(it * 128 + pix) * 256 + chs * 8;
    unsigned m = 0;
    #pragma unroll
    for (int tap = 0; tap < 9; ++tap) {
      const int dr = tap / 3 - 1, dc = tap % 3 - 1;
      if ((unsigned)(hh + dr) < 128u && (unsigned)(pix + dc) < 128u)
        m |= 1u << tap;
    }
    vmask[it] = m;
  }
  const unsigned short* zb = zerobuf + chq * 8;

  f32x4 acc[8][4];
  #pragma unroll
  for (int i = 0; i < 8; ++i)
    #pragma unroll
    for (int j = 0; j < 4; ++j) acc[i][j] = (f32x4){0.f, 0.f, 0.f, 0.f};

  auto stageB = [&](int ts) {  // B operand: 2 gld_lds
    const int tap = ts >> 3, kc = ts & 7;
    const int boffg = tap * 65536 + kc * 32;
    unsigned char* Bd = smem + 65536 + (size_t)(ts & 3) * 16384;
    #pragma unroll
    for (int it = 0; it < 2; ++it)
      gld_lds16(Bd + (it * 512 + tid) * 16, pB[it] + boffg);
  };
  auto stageA = [&](int ts) {  // A operand: 2 gld_lds
    const int tap = ts >> 3, kc = ts & 7;
    const int q = (tap * 11) >> 5;
    const int tapdelta = ((q - 1) * 128 + (tap - q * 3 - 1)) * 256 + kc * 32;
    unsigned char* Ad = smem + (size_t)(ts & 3) * 16384;
    #pragma unroll
    for (int it = 0; it < 2; ++it) {
      const unsigned short* src =
          ((vmask[it] >> tap) & 1) ? (pA[it] + tapdelta) : zb;
      gld_lds16(Ad + (it * 512 + tid) * 16, src);
    }
  };

#define LAUNDER(x) asm volatile("" : "+v"(x))

#define K3_STEP(T, VM, DO_STAGE)                                     \
  {                                                                  \
    bf16x8 af[8], fb[4];                                             \
    {                                                                \
      const unsigned short* Ab =                                     \
          (const unsigned short*)(smem + (size_t)((T) & 3) * 16384); \
      const unsigned short* Bb = (const unsigned short*)(            \
          smem + 65536 + (size_t)((T) & 3) * 16384);                 \
      _Pragma("unroll")                                              \
      for (int ni = 0; ni < 4; ++ni)                                 \
        fb[ni] = *(const bf16x8*)(Bb + boff[ni]);                    \
      _Pragma("unroll")                                              \
      for (int mi = 0; mi < 4; ++mi)                                 \
        af[mi] = *(const bf16x8*)(Ab + aoff[mi]);                    \
      if (DO_STAGE) stageB((T) + 3);                                 \
      asm volatile("" ::: "memory");                                 \
      __builtin_amdgcn_s_barrier();                                  \
      asm volatile("s_waitcnt lgkmcnt(0)" ::: "memory");             \
      _Pragma("unroll")                                              \
      for (int ni = 0; ni < 4; ++ni) LAUNDER(fb[ni]);                \
      _Pragma("unroll")                                              \
      for (int mi = 0; mi < 4; ++mi) LAUNDER(af[mi]);                \
      __builtin_amdgcn_sched_barrier(0);                             \
      __builtin_amdgcn_s_setprio(1);                                 \
      _Pragma("unroll")                                              \
      for (int mi = 0; mi < 4; ++mi)                                 \
        _Pragma("unroll")                                            \
        for (int ni = 0; ni < 4; ++ni)                               \
          acc[mi][ni] = __builtin_amdgcn_mfma_f32_16x16x32_bf16(     \
              af[mi], fb[ni], acc[mi][ni], 0, 0, 0);                 \
      __builtin_amdgcn_s_setprio(0);                                 \
      __builtin_amdgcn_sched_barrier(0);                             \
      asm volatile("" ::: "memory");                                 \
      __builtin_amdgcn_s_barrier();                                  \
      asm volatile("" ::: "memory");                                 \
      _Pragma("unroll")                                              \
      for (int mi = 4; mi < 8; ++mi)                                 \
        af[mi] = *(const bf16x8*)(Ab + aoff[mi]);                    \
      if (DO_STAGE) stageA((T) + 3);                                 \
      asm volatile("s_waitcnt vmcnt(" #VM ")" ::: "memory");         \
      __builtin_amdgcn_s_barrier();                                  \
      asm volatile("s_waitcnt lgkmcnt(0)" ::: "memory");             \
      _Pragma("unroll")                                              \
      for (int mi = 4; mi < 8; ++mi) LAUNDER(af[mi]);                \
      __builtin_amdgcn_sched_barrier(0);                             \
      __builtin_amdgcn_s_setprio(1);                                 \
      _Pragma("unroll")                                              \
      for (int mi = 4; mi < 8; ++mi)                                 \
        _Pragma("unroll")                                            \
        for (int ni = 0; ni < 4; ++ni)                               \
          acc[mi][ni] = __builtin_amdgcn_mfma_f32_16x16x32_bf16(     \
              af[mi], fb[ni], acc[mi][ni], 0, 0, 0);                 \
      __builtin_amdgcn_s_setprio(0);                                 \
      __builtin_amdgcn_sched_barrier(0);                             \
      asm volatile("" ::: "memory");                                 \
      __builtin_amdgcn_s_barrier();                                  \
      asm volatile("" ::: "memory");                                 \
    }                                                                \
  }

  // prologue: fill 3 ring slots; make stage(0) visible everywhere
  stageB(0); stageA(0);
  stageB(1); stageA(1);
  stageB(2); stageA(2);
  asm volatile("s_waitcnt vmcnt(8)" ::: "memory");
  __builtin_amdgcn_s_barrier();
  asm volatile("" ::: "memory");

  for (int t = 0; t < 69; ++t) K3_STEP(t, 8, true);
  K3_STEP(69, 4, false);
  K3_STEP(70, 0, false);
  K3_STEP(71, 0, false);
#undef K3_STEP
#undef LAUNDER

  // epilogue: +bias, fp32 store
  const int colg = wc * 64 + r15;
  float bias[4];
  #pragma unroll
  for (int ni = 0; ni < 4; ++ni) bias[ni] = b_def[colg + ni * 16];
  #pragma unroll
  for (int mi = 0; mi < 8; ++mi) {
    const int r0 = wr * 128 + mi * 16 + g4 * 4;
    #pragma unroll
    for (int j = 0; j < 4; ++j) {
      float* orow = out + ((size_t)mt * 256 + r0 + j) * 256 + colg;
      #pragma unroll
      for (int ni = 0; ni < 4; ++ni) orow[ni * 16] = acc[mi][ni][j] + bias[ni];
    }
  }
}

extern "C" void kernel_launch(void* const* d_in, const int* in_sizes, int n_in,
                              void* d_out, int out_size, void* d_ws, size_t ws_size,
                              hipStream_t stream) {
  const float* in = (const float*)d_in[0];     // (16,128,128,256)
  const float* w_off = (const float*)d_in[1];  // (3,3,256,2)
  const float* b_off = (const float*)d_in[2];  // (2,)
  const float* w_def = (const float*)d_in[3];  // (3,3,256,256)
  const float* b_def = (const float*)d_in[4];  // (256,)
  float* out = (float*)d_out;

  char* ws = (char*)d_ws;
  unsigned short* zerobuf = (unsigned short*)ws;                 // 4 KB zeros
  unsigned short* wT = (unsigned short*)(ws + 4096);             // 1,179,648 B
  unsigned short* samp = (unsigned short*)(ws + 4096 + 1179648); // 134,217,728 B

  hipMemsetAsync(ws, 0, 4096, stream);
  hipLaunchKernelGGL(k2_wT, dim3(2304), dim3(256), 0, stream, w_def, wT);
  hipLaunchKernelGGL(k1_offs_gather, dim3(2048), dim3(256), 0, stream,
                     in, w_off, b_off, samp);
  hipLaunchKernelGGL(k3_conv, dim3(1024), dim3(512), 0, stream,
                     samp, wT, b_def, out, zerobuf);
}

// Round 9
// 492.689 us; speedup vs baseline: 1.1060x; 1.1060x over previous
//
#include <hip/hip_runtime.h>
#include <hip/hip_bf16.h>

typedef __attribute__((ext_vector_type(8))) short bf16x8;
typedef __attribute__((ext_vector_type(4))) float f32x4;

__device__ __forceinline__ unsigned short f2bf(float f) {
  __hip_bfloat16 h = __float2bfloat16(f);
  return *reinterpret_cast<unsigned short*>(&h);
}

__device__ __forceinline__ void gld_lds16(void* lds, const void* g) {
  __builtin_amdgcn_global_load_lds(
      (const __attribute__((address_space(1))) unsigned int*)g,
      (__attribute__((address_space(3))) unsigned int*)lds, 16, 0, 0);
}

// ---------------------------------------------------------------------------
// Kernel 1: offset conv (fp64 accumulate) + gather + fp32->bf16 cast.
// (unchanged — isolate the k3 delta)
// ---------------------------------------------------------------------------
__global__ __launch_bounds__(256) void k1_offs_gather(
    const float* __restrict__ in, const float* __restrict__ w_off,
    const float* __restrict__ b_off, unsigned short* __restrict__ samp) {
  __shared__ float tile[3][128][34];
  __shared__ float wlf[9 * 64];
  __shared__ double dsum[2][128][2];
  __shared__ int lin_lds[128];

  const int bid = blockIdx.x;
  const int b = bid >> 7, h = bid & 127;
  const int t = threadIdx.x;
  const int w = t & 127, half = t >> 7, ch0 = half * 16;

  double a0 = 0.0, a1 = 0.0;

  for (int c0 = 0; c0 < 256; c0 += 32) {
    __syncthreads();
    for (int i = t; i < 576; i += 256) {
      int tap = i >> 6, r = i & 63;
      wlf[i] = w_off[tap * 512 + c0 * 2 + r];
    }
    for (int dr = 0; dr < 3; ++dr) {
      int hh = h + dr - 1;
      if ((unsigned)hh < 128u) {
        const float* rbase = in + ((size_t)(b * 128 + hh) * 128) * 256 + c0;
        #pragma unroll
        for (int it = 0; it < 4; ++it) {
          int idx = it * 256 + t;
          int ww = idx >> 3, cq = idx & 7;
          const float4 v = *(const float4*)(rbase + ww * 256 + cq * 4);
          float* dst = &tile[dr][ww][cq * 4];
          *(float2*)dst = make_float2(v.x, v.y);
          *(float2*)(dst + 2) = make_float2(v.z, v.w);
        }
      } else {
        #pragma unroll
        for (int it = 0; it < 4; ++it) {
          int idx = it * 256 + t;
          int ww = idx >> 3, cq = idx & 7;
          float* dst = &tile[dr][ww][cq * 4];
          *(float2*)dst = make_float2(0.f, 0.f);
          *(float2*)(dst + 2) = make_float2(0.f, 0.f);
        }
      }
    }
    __syncthreads();
    #pragma unroll
    for (int dr = 0; dr < 3; ++dr) {
      #pragma unroll
      for (int dc = 0; dc < 3; ++dc) {
        int wsrc = w + dc - 1;
        if ((unsigned)wsrc >= 128u) continue;
        const float2* tp2 = (const float2*)&tile[dr][wsrc][ch0];
        const float2* wp2 = (const float2*)&wlf[(dr * 3 + dc) * 64 + ch0 * 2];
        #pragma unroll
        for (int c2 = 0; c2 < 8; ++c2) {
          float2 v = tp2[c2];
          float2 wa = wp2[2 * c2];
          float2 wb = wp2[2 * c2 + 1];
          a0 += (double)v.x * (double)wa.x;
          a1 += (double)v.x * (double)wa.y;
          a0 += (double)v.y * (double)wb.x;
          a1 += (double)v.y * (double)wb.y;
        }
      }
    }
  }
  dsum[half][w][0] = a0;
  dsum[half][w][1] = a1;
  __syncthreads();
  if (t < 128) {
    double o0 = dsum[0][t][0] + dsum[1][t][0] + (double)b_off[0];
    double o1 = dsum[0][t][1] + dsum[1][t][1] + (double)b_off[1];
    double yd = (double)h + o0;
    double xd = (double)t + o1;
    yd = yd < 0.0 ? 0.0 : (yd > 127.0 ? 127.0 : yd);
    xd = xd < 0.0 ? 0.0 : (xd > 127.0 ? 127.0 : xd);
    int y = (int)yd, x = (int)xd;
    lin_lds[t] = y * 128 + x;
  }
  __syncthreads();
  const float* imgbase = in + (size_t)b * 16384 * 256;
  unsigned short* obase = samp + (size_t)bid * 128 * 256;
  for (int it = 0; it < 32; ++it) {
    int idx = it * 256 + t;
    int px = idx >> 6, cv = idx & 63;
    const float4 v = *(const float4*)(imgbase + (size_t)lin_lds[px] * 256 + cv * 4);
    ushort4 o;
    o.x = f2bf(v.x); o.y = f2bf(v.y); o.z = f2bf(v.z); o.w = f2bf(v.w);
    *(ushort4*)(obase + px * 256 + cv * 4) = o;
  }
}

// ---------------------------------------------------------------------------
// Kernel 2: w_def (3,3,256,256)[tap][k][n] fp32 -> wT[tap][n][k] bf16
// ---------------------------------------------------------------------------
__global__ __launch_bounds__(256) void k2_wT(const float* __restrict__ wdef,
                                             unsigned short* __restrict__ wT) {
  int g = blockIdx.x * 256 + threadIdx.x;
  int tap = g >> 16;
  int n = (g >> 8) & 255;
  int k = g & 255;
  wT[g] = f2bf(wdef[((size_t)tap * 256 + k) * 256 + n]);
}

// ---------------------------------------------------------------------------
// Kernel 3: implicit-GEMM 3x3 SAME conv, bf16 MFMA.
// REGISTER-PREFETCH schedule (round-8 structure, prologue race FIXED):
// fragments for step t are ds_read one step EARLY into alternating reg sets.
// Step t body:
//   lgkmcnt(0) gate (frags t landed) + launder + sched_barrier
//   -> one region: { reads(t+1) 12x ds_read || stage(t+3) 4x gld_lds ||
//                    32 MFMA(t) } forced interleave via sched_group_barrier
//      pattern 4x{MFMA 8, DS_READ 3, VMEM 1}
//   -> vmcnt(4) -> s_barrier.
// Ledger: END of step t guarantees stages <= t+2 landed (outstanding
// {t+2,t+3}=8, vmcnt(4) drains t+2). Body of step t reads slot t+1, needs
// START-of-t guarantee "<= t+1 landed": holds for t>=1 by induction; BASE
// CASE requires prologue vmcnt(4) (drain stages 0 AND 1) -- round 8's
// vmcnt(8) drained only stage 0 and raced slot 1 (absmax 0.675). Fixed.
// WAR: stage(t+3) writes slot (t-1)&3; its readers' lgkmcnt(0) at top of
// step t-1 precedes the end-of-(t-1) barrier < stage issue.
// Tail: vmcnt(4)@68, vmcnt(0)@69, vmcnt(0)@70, t=71 MFMA only.
// ---------------------------------------------------------------------------
struct Frags { bf16x8 a[8]; bf16x8 b[4]; };

__global__ __launch_bounds__(512, 2) void k3_conv(
    const unsigned short* __restrict__ samp, const unsigned short* __restrict__ wT,
    const float* __restrict__ b_def, float* __restrict__ out,
    const unsigned short* __restrict__ zerobuf) {
  __shared__ __align__(16) unsigned char smem[131072];  // A ring 64KB | B ring 64KB

  // T1: bijective XCD swizzle (grid 1024 % 8 == 0)
  const int bid0 = blockIdx.x;
  const int mt = (bid0 & 7) * 128 + (bid0 >> 3);
  const int bimg = mt >> 6;
  const int h0 = (mt & 63) * 2;

  const int tid = threadIdx.x;
  const int lane = tid & 63, wave = tid >> 6;
  const int wr = wave >> 2, wc = wave & 3;
  const int r15 = lane & 15, g4 = lane >> 4;
  const int g4eff = g4 ^ ((r15 >> 1) & 3);   // read-side bank swizzle

  // per-thread ds_read byte bases; frag (slot,mi): + slot*16384 + mi*1024
  const char* sA = (const char*)smem + (wr * 128 + r15) * 64 + g4eff * 16;
  const char* sB = (const char*)smem + 65536 + (wc * 64 + r15) * 64 + g4eff * 16;

  // ---- staging precompute (hoisted) ----
  const int chq = tid & 3;
  const int pix = tid >> 2;
  const int chs = chq ^ ((pix >> 1) & 3);  // inverse swizzle on global source
  const unsigned short* pA[2];
  const unsigned short* pB[2];
  unsigned vmask[2];
  #pragma unroll
  for (int it = 0; it < 2; ++it) {
    const int hh = h0 + it;
    pA[it] = samp + ((size_t)(bimg * 128 + hh) * 128 + pix) * 256 + chs * 8;
    pB[it] = wT + (size_t)(it * 128 + pix) * 256 + chs * 8;
    unsigned m = 0;
    #pragma unroll
    for (int tap = 0; tap < 9; ++tap) {
      const int dr = tap / 3 - 1, dc = tap % 3 - 1;
      if ((unsigned)(hh + dr) < 128u && (unsigned)(pix + dc) < 128u)
        m |= 1u << tap;
    }
    vmask[it] = m;
  }
  const unsigned short* zb = zerobuf + chq * 8;

  f32x4 acc[8][4];
  #pragma unroll
  for (int i = 0; i < 8; ++i)
    #pragma unroll
    for (int j = 0; j < 4; ++j) acc[i][j] = (f32x4){0.f, 0.f, 0.f, 0.f};

  auto stage = [&](int ts, int SLOT) {
    const int tap = ts >> 3, kc = ts & 7;
    const int q = (tap * 11) >> 5;
    const int tapdelta = ((q - 1) * 128 + (tap - q * 3 - 1)) * 256 + kc * 32;
    const int boffg = tap * 65536 + kc * 32;
    unsigned char* Ad = smem + SLOT * 16384;
    unsigned char* Bd = smem + 65536 + SLOT * 16384;
    #pragma unroll
    for (int it = 0; it < 2; ++it)
      gld_lds16(Bd + (it * 512 + tid) * 16, pB[it] + boffg);
    #pragma unroll
    for (int it = 0; it < 2; ++it) {
      const unsigned short* src =
          ((vmask[it] >> tap) & 1) ? (pA[it] + tapdelta) : zb;
      gld_lds16(Ad + (it * 512 + tid) * 16, src);
    }
  };

  auto readfr = [&](Frags& f, int SLOT) {
    #pragma unroll
    for (int ni = 0; ni < 4; ++ni)
      f.b[ni] = *(const bf16x8*)(sB + SLOT * 16384 + ni * 1024);
    #pragma unroll
    for (int mi = 0; mi < 8; ++mi)
      f.a[mi] = *(const bf16x8*)(sA + SLOT * 16384 + mi * 1024);
  };

  auto launder = [&](Frags& f) {
    #pragma unroll
    for (int i = 0; i < 8; ++i) asm volatile("" : "+v"(f.a[i]));
    #pragma unroll
    for (int i = 0; i < 4; ++i) asm volatile("" : "+v"(f.b[i]));
  };

  auto mfma32 = [&](Frags& f) {
    #pragma unroll
    for (int mi = 0; mi < 8; ++mi)
      #pragma unroll
      for (int ni = 0; ni < 4; ++ni)
        acc[mi][ni] = __builtin_amdgcn_mfma_f32_16x16x32_bf16(
            f.a[mi], f.b[ni], acc[mi][ni], 0, 0, 0);
  };

  Frags fr0, fr1;

#define K3_STEP(T_RT, SLOT_NXT, FR_CUR, FR_NXT, DO_READS, DO_STAGE, VMSTR) \
  {                                                                        \
    asm volatile("s_waitcnt lgkmcnt(0)" ::: "memory");                     \
    launder(FR_CUR);                                                       \
    __builtin_amdgcn_sched_barrier(0);                                     \
    __builtin_amdgcn_s_setprio(1);                                         \
    if (DO_READS) readfr(FR_NXT, SLOT_NXT);                                \
    if (DO_STAGE) stage((T_RT) + 3, ((SLOT_NXT) + 2) & 3);                 \
    mfma32(FR_CUR);                                                        \
    if (DO_READS && DO_STAGE) {                                            \
      _Pragma("unroll")                                                    \
      for (int u = 0; u < 4; ++u) {                                        \
        __builtin_amdgcn_sched_group_barrier(0x008, 8, 0);                 \
        __builtin_amdgcn_sched_group_barrier(0x100, 3, 0);                 \
        __builtin_amdgcn_sched_group_barrier(0x030, 1, 0);                 \
      }                                                                    \
    }                                                                      \
    __builtin_amdgcn_s_setprio(0);                                         \
    __builtin_amdgcn_sched_barrier(0);                                     \
    asm volatile("s_waitcnt " VMSTR ::: "memory");                         \
    __builtin_amdgcn_s_barrier();                                          \
    asm volatile("" ::: "memory");                                         \
  }

  // prologue: fill 3 ring slots; drain stages 0 AND 1 (base case of the
  // reads-one-early ledger); preload frags(0)
  stage(0, 0); stage(1, 1); stage(2, 2);
  asm volatile("s_waitcnt vmcnt(4)" ::: "memory");
  __builtin_amdgcn_s_barrier();
  asm volatile("" ::: "memory");
  readfr(fr0, 0);

  for (int tb = 0; tb < 68; tb += 4) {
    K3_STEP(tb + 0, 1, fr0, fr1, true, true, "vmcnt(4)");
    K3_STEP(tb + 1, 2, fr1, fr0, true, true, "vmcnt(4)");
    K3_STEP(tb + 2, 3, fr0, fr1, true, true, "vmcnt(4)");
    K3_STEP(tb + 3, 0, fr1, fr0, true, true, "vmcnt(4)");
  }
  K3_STEP(68, 1, fr0, fr1, true, true,  "vmcnt(4)");   // stages 71
  K3_STEP(69, 2, fr1, fr0, true, false, "vmcnt(0)");   // drain stage 71
  K3_STEP(70, 3, fr0, fr1, true, false, "vmcnt(0)");
  {  // t = 71: final, MFMA only
    asm volatile("s_waitcnt lgkmcnt(0)" ::: "memory");
    launder(fr1);
    __builtin_amdgcn_sched_barrier(0);
    mfma32(fr1);
  }
#undef K3_STEP

  // epilogue: +bias, fp32 store
  const int colg = wc * 64 + r15;
  float bias[4];
  #pragma unroll
  for (int ni = 0; ni < 4; ++ni) bias[ni] = b_def[colg + ni * 16];
  #pragma unroll
  for (int mi = 0; mi < 8; ++mi) {
    const int r0 = wr * 128 + mi * 16 + g4 * 4;
    #pragma unroll
    for (int j = 0; j < 4; ++j) {
      float* orow = out + ((size_t)mt * 256 + r0 + j) * 256 + colg;
      #pragma unroll
      for (int ni = 0; ni < 4; ++ni) orow[ni * 16] = acc[mi][ni][j] + bias[ni];
    }
  }
}

extern "C" void kernel_launch(void* const* d_in, const int* in_sizes, int n_in,
                              void* d_out, int out_size, void* d_ws, size_t ws_size,
                              hipStream_t stream) {
  const float* in = (const float*)d_in[0];     // (16,128,128,256)
  const float* w_off = (const float*)d_in[1];  // (3,3,256,2)
  const float* b_off = (const float*)d_in[2];  // (2,)
  const float* w_def = (const float*)d_in[3];  // (3,3,256,256)
  const float* b_def = (const float*)d_in[4];  // (256,)
  float* out = (float*)d_out;

  char* ws = (char*)d_ws;
  unsigned short* zerobuf = (unsigned short*)ws;                 // 4 KB zeros
  unsigned short* wT = (unsigned short*)(ws + 4096);             // 1,179,648 B
  unsigned short* samp = (unsigned short*)(ws + 4096 + 1179648); // 134,217,728 B

  hipMemsetAsync(ws, 0, 4096, stream);
  hipLaunchKernelGGL(k2_wT, dim3(2304), dim3(256), 0, stream, w_def, wT);
  hipLaunchKernelGGL(k1_offs_gather, dim3(2048), dim3(256), 0, stream,
                     in, w_off, b_off, samp);
  hipLaunchKernelGGL(k3_conv, dim3(1024), dim3(512), 0, stream,
                     samp, wT, b_def, out, zerobuf);
}